// Round 4
// baseline (138.680 us; speedup 1.0000x reference)
//
#include <hip/hip_runtime.h>

#define ACN_EPS   0.001f
#define TBL_N     2048
#define TBL_LO    -8.0f
#define TBL_SCALE 128.0f      // TBL_N / (HI-LO) = 2048/16
#define TBL_OFF   1024.0f     // -TBL_LO * TBL_SCALE
#define TBL_MAX_T 2047.999f

typedef float v4f __attribute__((ext_vector_type(4)));

// ---------------------------------------------------------------------------
// F(x): the exact reference math for one scalar x (all K=8 components).
// ---------------------------------------------------------------------------
__device__ __forceinline__ float acn_F(float x, const float* mu,
                                       const float* v, const float* pr) {
    float denom = 0.0f;
#pragma unroll
    for (int k = 0; k < 8; ++k) {
        float d = (x - mu[k]) / v[k];
        denom += pr[k] * expf(-0.5f * d * d);
    }
    float r = 0.0f;
#pragma unroll
    for (int k = 0; k < 8; ++k) {
        float ve  = v[k] + ACN_EPS;
        float d   = (x - mu[k]) / ve;
        float tau = pr[k] * expf(-0.5f * d * d) / (denom + ACN_EPS);
        float hat = (x - mu[k]) / sqrtf(ve);
        r += tau / sqrtf(pr[k] + ACN_EPS) * hat;
    }
    return r;
}

// ---------------------------------------------------------------------------
// Build the 2048-interval piecewise-linear table of F over [-8, 8] into d_ws.
// T[i] = (y_i, y_{i+1} - y_i).  One block; each thread derives the component
// params itself (8 scalars each — trivial).
// ---------------------------------------------------------------------------
__global__ void acn_build(const float* __restrict__ mean,
                          const float* __restrict__ variance,
                          const float* __restrict__ prior,
                          float2* __restrict__ T) {
    float mu[8], v[8], pr[8], e[8];
    float mx = -1e30f;
#pragma unroll
    for (int k = 0; k < 8; ++k) {
        mu[k] = mean[k];
        v[k]  = logf(1.0f + expf(variance[k]));   // softplus
        e[k]  = prior[k];
        mx = fmaxf(mx, e[k]);
    }
    float s = 0.0f;
#pragma unroll
    for (int k = 0; k < 8; ++k) { e[k] = expf(e[k] - mx); s += e[k]; }
#pragma unroll
    for (int k = 0; k < 8; ++k) pr[k] = e[k] / s;

    const float h = 1.0f / TBL_SCALE;
    for (int i = threadIdx.x; i < TBL_N; i += blockDim.x) {
        float x0 = TBL_LO + (float)i * h;
        float y0 = acn_F(x0,     mu, v, pr);
        float y1 = acn_F(x0 + h, mu, v, pr);
        T[i] = make_float2(y0, y1 - y0);
    }
}

// ---------------------------------------------------------------------------
// Main: stage table to LDS, then per element: scale/clamp/split x into
// (index, frac), one ds_read_b64 gather, one interp fma. Memory-bound.
// ---------------------------------------------------------------------------
__device__ __forceinline__ float acn_interp(const float2* tbl, float xx) {
    float t  = fmaf(xx, TBL_SCALE, TBL_OFF);
    t        = fminf(fmaxf(t, 0.0f), TBL_MAX_T);
    float tt = truncf(t);               // t >= 0, trunc == floor
    float f  = t - tt;
    float2 yd = tbl[(int)tt];
    return fmaf(yd.y, f, yd.x);
}

__device__ __forceinline__ v4f acn_interp4(const float2* tbl, v4f xv) {
    v4f r;
    r.x = acn_interp(tbl, xv.x);
    r.y = acn_interp(tbl, xv.y);
    r.z = acn_interp(tbl, xv.z);
    r.w = acn_interp(tbl, xv.w);
    return r;
}

__global__ __launch_bounds__(256) void acn_main(const v4f* __restrict__ x,
                                                v4f* __restrict__ out,
                                                const float2* __restrict__ T,
                                                int n4) {
    __shared__ float2 tbl[TBL_N];
    for (int i = threadIdx.x; i < TBL_N; i += 256) tbl[i] = T[i];
    __syncthreads();

    const int Tn  = gridDim.x * blockDim.x;
    const int idx = blockIdx.x * blockDim.x + threadIdx.x;

    if (n4 == 8 * Tn) {                 // fast path: 4 pipelined pair-iters
        v4f a = x[idx];
        v4f b = x[idx + Tn];
#pragma unroll
        for (int c = 0; c < 4; ++c) {
            const int i = idx + c * 2 * Tn;
            v4f an, bn;
            if (c < 3) {                // prefetch next pair before compute
                an = x[i + 2 * Tn];
                bn = x[i + 3 * Tn];
            }
            __builtin_nontemporal_store(acn_interp4(tbl, a), &out[i]);
            __builtin_nontemporal_store(acn_interp4(tbl, b), &out[i + Tn]);
            if (c < 3) { a = an; b = bn; }
        }
    } else {
        for (int i = idx; i < n4; i += Tn) {
            __builtin_nontemporal_store(acn_interp4(tbl, x[i]), &out[i]);
        }
    }
}

extern "C" void kernel_launch(void* const* d_in, const int* in_sizes, int n_in,
                              void* d_out, int out_size, void* d_ws, size_t ws_size,
                              hipStream_t stream) {
    const float* x        = (const float*)d_in[0];
    const float* mean     = (const float*)d_in[1];
    const float* variance = (const float*)d_in[2];
    const float* prior    = (const float*)d_in[3];
    float* out = (float*)d_out;
    float2* T  = (float2*)d_ws;   // 2048 * 8 B = 16 KiB table

    acn_build<<<1, 256, 0, stream>>>(mean, variance, prior, T);

    int n4 = out_size / 4;        // 4,194,304 = 8 * (2048*256)
    const int block = 256;
    const int grid  = 2048;       // 8 blocks/CU, 32 waves/CU; LDS 8*16K=128K/CU
    acn_main<<<grid, block, 0, stream>>>((const v4f*)x, (v4f*)out, T, n4);
}

// Round 5
// 118.854 us; speedup vs baseline: 1.1668x; 1.1668x over previous
//
#include <hip/hip_runtime.h>

#define ACN_EPS   0.001f
#define ACN_LOG2E 1.4426950408889634f
#define TBL_N     2048
#define TBL_LO    -8.0f
#define TBL_SCALE 128.0f      // TBL_N / (HI-LO) = 2048/16
#define TBL_OFF   1024.0f     // -TBL_LO * TBL_SCALE
#define TBL_MAX_T 2047.999f

typedef float v4f __attribute__((ext_vector_type(4)));

// ---------------------------------------------------------------------------
// Build the 2048-interval piecewise-linear table of F over [-8, 8] into d_ws.
// T[i] = (y_i, y_{i+1} - y_i).  2048 threads, ONE interval each (R4 post-
// mortem: 1-block serial build with libm divides was a ~30 µs serial tail).
// F evaluated in exp2-folded form: no divides in the k-loop, exact exponents.
// ---------------------------------------------------------------------------
__device__ __forceinline__ float acn_F_fast(float x, const float* mu,
                                            const float* s1, const float* lp,
                                            const float* s2, const float* lw) {
    float denom = 0.0f, S = 0.0f;
#pragma unroll
    for (int k = 0; k < 8; ++k) {
        float d  = x - mu[k];
        float d2 = d * d;
        denom += __builtin_amdgcn_exp2f(fmaf(s1[k], d2, lp[k]));
        S = fmaf(__builtin_amdgcn_exp2f(fmaf(s2[k], d2, lw[k])), d, S);
    }
    return S * __builtin_amdgcn_rcpf(denom + ACN_EPS);
}

__global__ void acn_build(const float* __restrict__ mean,
                          const float* __restrict__ variance,
                          const float* __restrict__ prior,
                          float2* __restrict__ T) {
    int i = blockIdx.x * blockDim.x + threadIdx.x;
    if (i >= TBL_N) return;

    float mu[8], s1[8], lp[8], s2[8], lw[8], e[8];
    float mx = -1e30f;
#pragma unroll
    for (int k = 0; k < 8; ++k) {
        e[k] = prior[k];
        mx = fmaxf(mx, e[k]);
    }
    float sum = 0.0f;
#pragma unroll
    for (int k = 0; k < 8; ++k) { e[k] = expf(e[k] - mx); sum += e[k]; }
#pragma unroll
    for (int k = 0; k < 8; ++k) {
        float pk = e[k] / sum;                       // softmax(prior)
        float v  = logf(1.0f + expf(variance[k]));   // softplus(variance)
        float ve = v + ACN_EPS;
        mu[k] = mean[k];
        s1[k] = -0.5f * ACN_LOG2E / (v * v);
        s2[k] = -0.5f * ACN_LOG2E / (ve * ve);
        lp[k] = log2f(pk);
        lw[k] = lp[k] - 0.5f * log2f(pk + ACN_EPS) - 0.5f * log2f(ve);
    }

    const float h  = 1.0f / TBL_SCALE;
    float x0 = TBL_LO + (float)i * h;
    float y0 = acn_F_fast(x0,     mu, s1, lp, s2, lw);
    float y1 = acn_F_fast(x0 + h, mu, s1, lp, s2, lw);
    T[i] = make_float2(y0, y1 - y0);
}

// ---------------------------------------------------------------------------
// Main: stage table to LDS, then per element: scale/clamp/split x into
// (index, frac), one ds_read_b64 gather, one interp fma. Memory-bound.
// ---------------------------------------------------------------------------
__device__ __forceinline__ float acn_interp(const float2* tbl, float xx) {
    float t  = fmaf(xx, TBL_SCALE, TBL_OFF);
    t        = fminf(fmaxf(t, 0.0f), TBL_MAX_T);
    float tt = truncf(t);               // t >= 0, trunc == floor
    float f  = t - tt;
    float2 yd = tbl[(int)tt];
    return fmaf(yd.y, f, yd.x);
}

__device__ __forceinline__ v4f acn_interp4(const float2* tbl, v4f xv) {
    v4f r;
    r.x = acn_interp(tbl, xv.x);
    r.y = acn_interp(tbl, xv.y);
    r.z = acn_interp(tbl, xv.z);
    r.w = acn_interp(tbl, xv.w);
    return r;
}

__global__ __launch_bounds__(256) void acn_main(const v4f* __restrict__ x,
                                                v4f* __restrict__ out,
                                                const float2* __restrict__ T,
                                                int n4) {
    __shared__ float2 tbl[TBL_N];
    for (int i = threadIdx.x; i < TBL_N; i += 256) tbl[i] = T[i];
    __syncthreads();

    const int Tn  = gridDim.x * blockDim.x;
    const int idx = blockIdx.x * blockDim.x + threadIdx.x;

    if (n4 == 8 * Tn) {                 // fast path: 4 pipelined pair-iters
        v4f a = x[idx];
        v4f b = x[idx + Tn];
#pragma unroll
        for (int c = 0; c < 4; ++c) {
            const int i = idx + c * 2 * Tn;
            v4f an, bn;
            if (c < 3) {                // prefetch next pair before compute
                an = x[i + 2 * Tn];
                bn = x[i + 3 * Tn];
            }
            __builtin_nontemporal_store(acn_interp4(tbl, a), &out[i]);
            __builtin_nontemporal_store(acn_interp4(tbl, b), &out[i + Tn]);
            if (c < 3) { a = an; b = bn; }
        }
    } else {
        for (int i = idx; i < n4; i += Tn) {
            __builtin_nontemporal_store(acn_interp4(tbl, x[i]), &out[i]);
        }
    }
}

extern "C" void kernel_launch(void* const* d_in, const int* in_sizes, int n_in,
                              void* d_out, int out_size, void* d_ws, size_t ws_size,
                              hipStream_t stream) {
    const float* x        = (const float*)d_in[0];
    const float* mean     = (const float*)d_in[1];
    const float* variance = (const float*)d_in[2];
    const float* prior    = (const float*)d_in[3];
    float* out = (float*)d_out;
    float2* T  = (float2*)d_ws;   // 2048 * 8 B = 16 KiB table

    acn_build<<<TBL_N / 256, 256, 0, stream>>>(mean, variance, prior, T);

    int n4 = out_size / 4;        // 4,194,304 = 8 * (2048*256)
    const int block = 256;
    const int grid  = 2048;       // 8 blocks/CU, 32 waves/CU; LDS 8*16K=128K/CU
    acn_main<<<grid, block, 0, stream>>>((const v4f*)x, (v4f*)out, T, n4);
}

// Round 6
// 113.171 us; speedup vs baseline: 1.2254x; 1.0502x over previous
//
#include <hip/hip_runtime.h>
#include <hip/hip_fp16.h>

#define ACN_EPS   0.001f
#define ACN_LOG2E 1.4426950408889634f
#define ACN_LN2   0.6931471805599453f
#define TBL_N     2048
#define TBL_LO    -8.0f
#define TBL_SCALE 128.0f      // TBL_N / (HI-LO) = 2048/16
#define TBL_OFF   1024.0f     // -TBL_LO * TBL_SCALE
#define TBL_MAX_T 2047.999f

typedef float v4f  __attribute__((ext_vector_type(4)));
typedef unsigned int u32;
typedef u32 v4u __attribute__((ext_vector_type(4)));

// ---------------------------------------------------------------------------
// Build: 2048-interval piecewise-linear table of F over [-8, 8], each entry
// packed as f16x2 (y0, dy) in one dword. 8 blocks x 256 threads, one interval
// per thread. All-intrinsic math (R5 post-mortem: libm prep was the tail).
// ---------------------------------------------------------------------------
__device__ __forceinline__ float acn_F_fast(float x, const float* mu,
                                            const float* s1, const float* lp,
                                            const float* s2, const float* lw) {
    float denom = 0.0f, S = 0.0f;
#pragma unroll
    for (int k = 0; k < 8; ++k) {
        float d  = x - mu[k];
        float d2 = d * d;
        denom += __builtin_amdgcn_exp2f(fmaf(s1[k], d2, lp[k]));
        S = fmaf(__builtin_amdgcn_exp2f(fmaf(s2[k], d2, lw[k])), d, S);
    }
    return S * __builtin_amdgcn_rcpf(denom + ACN_EPS);
}

__global__ void acn_build(const float* __restrict__ mean,
                          const float* __restrict__ variance,
                          const float* __restrict__ prior,
                          u32* __restrict__ T) {
    int i = blockIdx.x * blockDim.x + threadIdx.x;
    if (i >= TBL_N) return;

    float mu[8], s1[8], lp[8], s2[8], lw[8], e[8];
    float mx = -1e30f;
#pragma unroll
    for (int k = 0; k < 8; ++k) { e[k] = prior[k]; mx = fmaxf(mx, e[k]); }
    float sum = 0.0f;
#pragma unroll
    for (int k = 0; k < 8; ++k) {
        e[k] = __builtin_amdgcn_exp2f((e[k] - mx) * ACN_LOG2E);
        sum += e[k];
    }
    float rs = __builtin_amdgcn_rcpf(sum);
#pragma unroll
    for (int k = 0; k < 8; ++k) {
        float pk = e[k] * rs;                                 // softmax(prior)
        // softplus(v) = ln(1 + e^v) = log2(1 + 2^(v*log2e)) * ln2
        float v  = __builtin_amdgcn_logf(1.0f +
                     __builtin_amdgcn_exp2f(variance[k] * ACN_LOG2E)) * ACN_LN2;
        float ve = v + ACN_EPS;
        float rv  = __builtin_amdgcn_rcpf(v);
        float rve = __builtin_amdgcn_rcpf(ve);
        mu[k] = mean[k];
        s1[k] = -0.5f * ACN_LOG2E * rv * rv;
        s2[k] = -0.5f * ACN_LOG2E * rve * rve;
        lp[k] = __builtin_amdgcn_logf(pk);
        lw[k] = lp[k] - 0.5f * __builtin_amdgcn_logf(pk + ACN_EPS)
                      - 0.5f * __builtin_amdgcn_logf(ve);
    }

    const float h  = 1.0f / TBL_SCALE;
    float x0 = TBL_LO + (float)i * h;
    float y0 = acn_F_fast(x0,     mu, s1, lp, s2, lw);
    float y1 = acn_F_fast(x0 + h, mu, s1, lp, s2, lw);
    __half2 hv = __halves2half2(__float2half(y0), __float2half(y1 - y0));
    T[i] = *(const u32*)&hv;
}

// ---------------------------------------------------------------------------
// Main: stage 8 KB packed table to LDS; per element: fma/med3/cvt -> one
// ds_read_b32 gather -> 2x cvt_f32_f16 -> interp fma. Memory-bound.
// ---------------------------------------------------------------------------
__device__ __forceinline__ float acn_interp(const u32* tbl, float xx) {
    float t  = fmaf(xx, TBL_SCALE, TBL_OFF);
    t        = __builtin_amdgcn_fmed3f(t, 0.0f, TBL_MAX_T);
    int   ii = (int)t;
    float f  = t - (float)ii;
    u32 u = tbl[ii];
    __half2 hv = *(const __half2*)&u;
    return fmaf(__high2float(hv), f, __low2float(hv));
}

__device__ __forceinline__ v4f acn_interp4(const u32* tbl, v4f xv) {
    v4f r;
    r.x = acn_interp(tbl, xv.x);
    r.y = acn_interp(tbl, xv.y);
    r.z = acn_interp(tbl, xv.z);
    r.w = acn_interp(tbl, xv.w);
    return r;
}

__global__ __launch_bounds__(256) void acn_main(const v4f* __restrict__ x,
                                                v4f* __restrict__ out,
                                                const v4u* __restrict__ T,
                                                int n4) {
    __shared__ u32 tbl[TBL_N];

    const int Tn  = gridDim.x * blockDim.x;
    const int idx = blockIdx.x * blockDim.x + threadIdx.x;

    if (n4 == 8 * Tn) {                 // fast path
        // Issue first-pair global loads BEFORE staging so they fly during it.
        v4f a = x[idx];
        v4f b = x[idx + Tn];

        // Stage packed table: 2048 dwords = 512 uint4, 2 per thread.
        v4u t0 = T[threadIdx.x];
        v4u t1 = T[threadIdx.x + 256];
        *(v4u*)&tbl[threadIdx.x * 4]         = t0;
        *(v4u*)&tbl[(threadIdx.x + 256) * 4] = t1;
        __syncthreads();

#pragma unroll
        for (int c = 0; c < 4; ++c) {
            const int i = idx + c * 2 * Tn;
            v4f an, bn;
            if (c < 3) {                // prefetch next pair before compute
                an = x[i + 2 * Tn];
                bn = x[i + 3 * Tn];
            }
            __builtin_nontemporal_store(acn_interp4(tbl, a), &out[i]);
            __builtin_nontemporal_store(acn_interp4(tbl, b), &out[i + Tn]);
            if (c < 3) { a = an; b = bn; }
        }
    } else {                            // generic fallback
        for (int i = threadIdx.x; i < TBL_N / 4; i += 256)
            *(v4u*)&tbl[i * 4] = T[i];
        __syncthreads();
        for (int i = idx; i < n4; i += Tn) {
            __builtin_nontemporal_store(acn_interp4(tbl, x[i]), &out[i]);
        }
    }
}

extern "C" void kernel_launch(void* const* d_in, const int* in_sizes, int n_in,
                              void* d_out, int out_size, void* d_ws, size_t ws_size,
                              hipStream_t stream) {
    const float* x        = (const float*)d_in[0];
    const float* mean     = (const float*)d_in[1];
    const float* variance = (const float*)d_in[2];
    const float* prior    = (const float*)d_in[3];
    float* out = (float*)d_out;
    u32*   T   = (u32*)d_ws;      // 2048 * 4 B = 8 KiB packed table

    acn_build<<<TBL_N / 256, 256, 0, stream>>>(mean, variance, prior, T);

    int n4 = out_size / 4;        // 4,194,304 = 8 * (2048*256)
    const int block = 256;
    const int grid  = 2048;       // 8 blocks/CU; LDS 8*8K = 64K/CU
    acn_main<<<grid, block, 0, stream>>>((const v4f*)x, (v4f*)out,
                                         (const v4u*)T, n4);
}